// Round 5
// baseline (21804.590 us; speedup 1.0000x reference)
//
#include <hip/hip_runtime.h>
#include <hip/hip_fp16.h>
#include <cmath>

// ---------------------------------------------------------------------------
// LMU fused recurrence.  Merged formulation: one 128x1536 @ 1536x1536 GEMM per
// step (tanh on first 1024 cols, linear on last 512), x-dependent rank-1 bias.
// Persistent kernel, 192 WGs x 256 thr (1 WG/CU), 2 independent batch groups
// x 96 WGs, double-buffered state in __device__ globals.
// Precision (verified r3/r4, absmax 4.9e-4): f16 hi/lo for weights AND state
// (lo planes scaled x2048), fp32 MFMA accumulate, 3 products.
// r5 changes: NO agent fences in the step loop (r4: 24 wbl2 + 24 inv per XCD
// per step serialized at L2 = the 21us/step stall).  State reads/writes are
// volatile (sc0 sc1: bypass non-coherent L1/L2, hit LLC coherence point
// directly); barrier is a monotone relaxed arrival counter, zero cache ops.
// ---------------------------------------------------------------------------

typedef _Float16 half8 __attribute__((ext_vector_type(8)));
typedef float floatx4 __attribute__((ext_vector_type(4)));

#define NSTATE   1536
#define BATCH    128
#define TSTEPS   784
#define KTILES   48                 // 1536 / 32
#define GRP_WGS  96                 // WGs per batch group
#define WPW      24576              // weight elems per WG slice (16 cols * 1536)
#define LO_SCALE 2048.0f
#define LO_INV   (1.0f / 2048.0f)

// All scratch in device globals: no dependence on ws_size, no hipMalloc.
__device__ __align__(16) _Float16 g_Whi[96 * WPW];
__device__ __align__(16) _Float16 g_Wlo[96 * WPW];
__device__ float    g_wb[NSTATE];
__device__ float    g_WmA[1024 * 512];
__device__ float    g_WmB[1024];
__device__ __align__(16) _Float16 g_Shi[2 * BATCH * NSTATE];
__device__ __align__(16) _Float16 g_Slo[2 * BATCH * NSTATE];
__device__ unsigned g_bar[256];

// W_mB[i] = sum_c W_m[i,c] * BT[c]   (one wave per row, shuffle reduce)
__global__ void prep_wmb(const float* __restrict__ Wm, const float* __restrict__ BT) {
    int row  = blockIdx.x * 4 + (threadIdx.x >> 6);
    int lane = threadIdx.x & 63;
    float s = 0.f;
    for (int c = lane; c < 512; c += 64) s += Wm[row * 512 + c] * BT[c];
    for (int o = 32; o; o >>= 1) s += __shfl_down(s, o);
    if (lane == 0) g_WmB[row] = s;
}

// W_mA = W_m @ (I + AT) : tiled 32x32, fp32
__global__ void prep_wma(const float* __restrict__ Wm, const float* __restrict__ AT) {
    __shared__ float As[32][33], Bs[32][33];
    int d0 = blockIdx.x * 32, i0 = blockIdx.y * 32;
    int tx = threadIdx.x & 31, ty = threadIdx.x >> 5;   // ty in 0..7
    float acc[4];
#pragma unroll
    for (int r = 0; r < 4; ++r) acc[r] = Wm[(i0 + ty + 8 * r) * 512 + d0 + tx];
    for (int c0 = 0; c0 < 512; c0 += 32) {
#pragma unroll
        for (int r = 0; r < 4; ++r) {
            As[ty + 8 * r][tx] = Wm[(i0 + ty + 8 * r) * 512 + c0 + tx];
            Bs[ty + 8 * r][tx] = AT[(c0 + ty + 8 * r) * 512 + d0 + tx];
        }
        __syncthreads();
#pragma unroll
        for (int c = 0; c < 32; ++c)
#pragma unroll
            for (int r = 0; r < 4; ++r) acc[r] += As[ty + 8 * r][c] * Bs[c][tx];
        __syncthreads();
    }
#pragma unroll
    for (int r = 0; r < 4; ++r) g_WmA[(i0 + ty + 8 * r) * 512 + d0 + tx] = acc[r];
}

// Build W_full in MFMA-B-fragment-swizzled order, split f16 hi/lo (lo x2048).
// swizzled index s = ((p*48 + kt)*64 + lane)*8 + j
//   n = p*16 + (lane&15),  k = kt*32 + ((lane>>4)&3)*8 + j
__global__ void prep_wfull(const float* __restrict__ Wh, const float* __restrict__ AT,
                           const float* __restrict__ BT, const float* __restrict__ eh,
                           const float* __restrict__ em, const float* __restrict__ ex,
                           const float* __restrict__ Wx) {
    int s = blockIdx.x * 256 + threadIdx.x;     // [0, 96*48*64*8) exactly
    int j8 = s & 7;
    int t = s >> 3;
    int lane = t & 63;
    t >>= 6;
    int kt = t % 48;
    int p = t / 48;
    int n = p * 16 + (lane & 15);
    int k = kt * 32 + ((lane >> 4) & 3) * 8 + j8;

    float w;
    if (n < 1024) {
        if (k < 1024) w = Wh[n * 1024 + k] + g_WmB[n] * eh[k];
        else          w = g_WmA[n * 512 + (k - 1024)] + g_WmB[n] * em[k - 1024];
    } else {
        int c = n - 1024;
        if (k < 1024) w = BT[c] * eh[k];
        else {
            int d = k - 1024;
            w = ((c == d) ? 1.f : 0.f) + AT[c * 512 + d] + BT[c] * em[d];
        }
    }
    _Float16 hi = (_Float16)w;
    g_Whi[s] = hi;
    g_Wlo[s] = (_Float16)((w - (float)hi) * LO_SCALE);

    if (s < NSTATE) {
        float b = (s < 1024) ? (Wx[s] + ex[0] * g_WmB[s]) : (BT[s - 1024] * ex[0]);
        g_wb[s] = b;
    }
    if (s < 2 * BATCH * NSTATE) { g_Shi[s] = (_Float16)0.f; g_Slo[s] = (_Float16)0.f; }
    if (s < 256) g_bar[s] = 0u;
}

__launch_bounds__(256, 1)
__global__ void lmu_persist(const float* __restrict__ inputs,
                            const float* __restrict__ Wd, const float* __restrict__ bd,
                            float* __restrict__ out) {
    __shared__ half8 lwh[KTILES * 64];          // W_hi slice: 48 KB
    __shared__ half8 lwl[KTILES * 64];          // W_lo slice: 48 KB (96 KB total)

    const int tid = threadIdx.x;
    const int bid = blockIdx.x;
    const int g = (bid >> 2) & 1;               // batch group
    const int p = (bid >> 3) * 4 + (bid & 3);   // column tile [0,96)

    // stage W_hi + W_lo (global, swizzled-linear) -> LDS
    {
        const half8* srcH = (const half8*)(g_Whi + (size_t)p * WPW);
        const half8* srcL = (const half8*)(g_Wlo + (size_t)p * WPW);
        for (int i = tid; i < WPW / 8; i += 256) { lwh[i] = srcH[i]; lwl[i] = srcL[i]; }
    }

    const int lane = tid & 63, wv = tid >> 6;
    const int quad = lane >> 4, l16 = lane & 15;
    const int b0 = g * 64 + wv * 16;            // this wave's 16-row block
    const int n = p * 16 + l16;                 // this lane's output column
    const float wbv = g_wb[n];
    const bool do_tanh = (p < 64);
    unsigned* cnt = g_bar + g * 128;            // monotone arrival counter

    __syncthreads();

    const int rowA = b0 + l16;                  // A-fragment row for this lane
    const int kbase = quad * 8;

    int buf = 0;
    for (int t = 0; t < TSTEPS; ++t) {
        // volatile (sc0 sc1) state reads: coherent, bypass stale L1/L2
        const volatile _Float16* shr = g_Shi + buf * BATCH * NSTATE + rowA * NSTATE + kbase;
        const volatile _Float16* slr = g_Slo + buf * BATCH * NSTATE + rowA * NSTATE + kbase;

        // x_t for epilogue (read-only input: normal cached load, L2 stays warm)
        const float* xt = inputs + t * BATCH;
        float xv[4];
#pragma unroll
        for (int r = 0; r < 4; ++r) xv[r] = xt[b0 + quad * 4 + r];

        floatx4 aA[2], aB[2], aC[2];
#pragma unroll
        for (int q = 0; q < 2; ++q) { aA[q] = (floatx4)0.f; aB[q] = (floatx4)0.f; aC[q] = (floatx4)0.f; }

#pragma unroll
        for (int kt = 0; kt < KTILES; ++kt) {
            half8 ah = *(const volatile half8*)(shr + kt * 32);
            half8 al = *(const volatile half8*)(slr + kt * 32);
            half8 bh = lwh[kt * 64 + lane];
            half8 bl = lwl[kt * 64 + lane];
            aA[kt & 1] = __builtin_amdgcn_mfma_f32_16x16x32_f16(ah, bh, aA[kt & 1], 0, 0, 0);
            aB[kt & 1] = __builtin_amdgcn_mfma_f32_16x16x32_f16(al, bh, aB[kt & 1], 0, 0, 0);
            aC[kt & 1] = __builtin_amdgcn_mfma_f32_16x16x32_f16(ah, bl, aC[kt & 1], 0, 0, 0);
        }

        // epilogue: bias + activation, split hi/lo, volatile store (write to LLC)
        const int nbuf = buf ^ 1;
        volatile _Float16* dh = g_Shi + nbuf * BATCH * NSTATE;
        volatile _Float16* dl = g_Slo + nbuf * BATCH * NSTATE;
#pragma unroll
        for (int r = 0; r < 4; ++r) {
            int b = b0 + quad * 4 + r;
            float v = (aA[0][r] + aA[1][r])
                    + ((aB[0][r] + aB[1][r]) + (aC[0][r] + aC[1][r])) * LO_INV;
            v += xv[r] * wbv;
            if (do_tanh) v = tanhf(v);
            _Float16 hi = (_Float16)v;
            dh[b * NSTATE + n] = hi;
            dl[b * NSTATE + n] = (_Float16)((v - (float)hi) * LO_SCALE);
        }

        // ---- group barrier: monotone arrival counter, zero cache ops ----
        __builtin_amdgcn_fence(__ATOMIC_RELEASE, "workgroup");  // compiler order only
        __syncthreads();                        // drains vmcnt: stores are at LLC
        if (tid == 0) {
            __hip_atomic_fetch_add(cnt, 1u, __ATOMIC_RELAXED,
                                   __HIP_MEMORY_SCOPE_AGENT);
            const unsigned target = (unsigned)GRP_WGS * (unsigned)(t + 1);
            int spin = 0;
            while (__hip_atomic_load(cnt, __ATOMIC_RELAXED,
                                     __HIP_MEMORY_SCOPE_AGENT) < target) {
                __builtin_amdgcn_s_sleep(1);
                if (++spin > (1 << 16)) break;              // deadman: no hang
            }
        }
        __syncthreads();
        __builtin_amdgcn_fence(__ATOMIC_ACQUIRE, "workgroup"); // compiler order only
        buf = nbuf;
    }

    // final epilogue: logits + softmax. WGs p<64 each own one batch row. buf==0.
    if (p < 64) {
        int b = g * 64 + p;
        const volatile _Float16* sh = g_Shi + b * NSTATE;
        const volatile _Float16* sl = g_Slo + b * NSTATE;
        __syncthreads();                         // smem reuse
        float* red = (float*)lwh;                // [16 chunks][16 cols] + [10 logits]
        int c = tid & 15, chunk = tid >> 4;
        float part = 0.f;
        if (c < 10) {
            for (int i = chunk * 64; i < chunk * 64 + 64; ++i)
                part += ((float)sh[i] + (float)sl[i] * LO_INV) * Wd[c * 1024 + i];
        }
        red[chunk * 16 + c] = part;
        __syncthreads();
        if (tid < 10) {
            float lg = bd[tid];
            for (int q = 0; q < 16; ++q) lg += red[q * 16 + tid];
            red[256 + tid] = lg;
        }
        __syncthreads();
        if (tid < 10) {
            float mx = red[256];
            for (int q = 1; q < 10; ++q) mx = fmaxf(mx, red[256 + q]);
            float sm = 0.f;
            for (int q = 0; q < 10; ++q) sm += expf(red[256 + q] - mx);
            out[b * 10 + tid] = expf(red[256 + tid] - mx) / sm;
        }
    }
}

extern "C" void kernel_launch(void* const* d_in, const int* in_sizes, int n_in,
                              void* d_out, int out_size, void* d_ws, size_t ws_size,
                              hipStream_t stream) {
    const float* inputs = (const float*)d_in[0];
    const float* e_x    = (const float*)d_in[1];
    const float* e_h    = (const float*)d_in[2];
    const float* e_m    = (const float*)d_in[3];
    const float* W_x    = (const float*)d_in[4];
    const float* W_h    = (const float*)d_in[5];
    const float* W_m    = (const float*)d_in[6];
    const float* AT     = (const float*)d_in[7];
    const float* BT     = (const float*)d_in[8];
    const float* W_d    = (const float*)d_in[9];
    const float* b_d    = (const float*)d_in[10];
    (void)d_ws; (void)ws_size; (void)in_sizes; (void)n_in;

    prep_wmb<<<256, 256, 0, stream>>>(W_m, BT);
    prep_wma<<<dim3(16, 32), 256, 0, stream>>>(W_m, AT);
    prep_wfull<<<9216, 256, 0, stream>>>(W_h, AT, BT, e_h, e_m, e_x, W_x);

    lmu_persist<<<192, 256, 0, stream>>>(inputs, W_d, b_d, (float*)d_out);
}

// Round 6
// 16878.561 us; speedup vs baseline: 1.2919x; 1.2919x over previous
//
#include <hip/hip_runtime.h>
#include <hip/hip_fp16.h>
#include <cmath>

// ---------------------------------------------------------------------------
// LMU fused recurrence.  One 128x1536 @ 1536x1536 GEMM per step (tanh on
// first 1024 cols, linear on last 512), x-dependent rank-1 bias.
// Persistent kernel, 192 WGs x 256 thr (1 WG/CU), 2 batch groups x 96 WGs.
// Precision (verified r3-r5, absmax 4.9e-4): f16 hi/lo weights AND state
// (lo planes x2048), fp32 MFMA accumulate, 3 products.
// r6 changes vs r5:
//  - state LOADS are normal cached (L2 serves 12 WGs/XCD from one fill;
//    r5's LLC-bypass loads cost ~+6us/step),
//  - state STORES stay volatile write-through (LLC always fresh -> L2 never
//    dirty -> NO release/wbl2 walk needed),
//  - ONE acquire(agent) fence per wave per step after the barrier (clean-L2
//    inv, cheap per r4 evidence),
//  - hierarchical barrier: 12 leaf counters (8 WGs) + root + go words, each
//    in its own 256B sector, all RELAXED + s_sleep backoff.  Kills the flat
//    96-arrival/95-poller single-line convoy (~20us/step in r4/r5).
// ---------------------------------------------------------------------------

typedef _Float16 half8 __attribute__((ext_vector_type(8)));
typedef float floatx4 __attribute__((ext_vector_type(4)));

#define NSTATE   1536
#define BATCH    128
#define TSTEPS   784
#define KTILES   48                 // 1536 / 32
#define GRP_WGS  96                 // WGs per batch group
#define WPW      24576              // weight elems per WG slice (16 cols * 1536)
#define LO_SCALE 2048.0f
#define LO_INV   (1.0f / 2048.0f)

// All scratch in device globals: no dependence on ws_size, no hipMalloc.
__device__ __align__(16) _Float16 g_Whi[96 * WPW];
__device__ __align__(16) _Float16 g_Wlo[96 * WPW];
__device__ float    g_wb[NSTATE];
__device__ float    g_WmA[1024 * 512];
__device__ float    g_WmB[1024];
__device__ __align__(16) _Float16 g_Shi[2 * BATCH * NSTATE];
__device__ __align__(16) _Float16 g_Slo[2 * BATCH * NSTATE];
__device__ unsigned g_bar[4096];    // 2 groups x 2048; 256B-sector counters

// W_mB[i] = sum_c W_m[i,c] * BT[c]   (one wave per row, shuffle reduce)
__global__ void prep_wmb(const float* __restrict__ Wm, const float* __restrict__ BT) {
    int row  = blockIdx.x * 4 + (threadIdx.x >> 6);
    int lane = threadIdx.x & 63;
    float s = 0.f;
    for (int c = lane; c < 512; c += 64) s += Wm[row * 512 + c] * BT[c];
    for (int o = 32; o; o >>= 1) s += __shfl_down(s, o);
    if (lane == 0) g_WmB[row] = s;
}

// W_mA = W_m @ (I + AT) : tiled 32x32, fp32
__global__ void prep_wma(const float* __restrict__ Wm, const float* __restrict__ AT) {
    __shared__ float As[32][33], Bs[32][33];
    int d0 = blockIdx.x * 32, i0 = blockIdx.y * 32;
    int tx = threadIdx.x & 31, ty = threadIdx.x >> 5;   // ty in 0..7
    float acc[4];
#pragma unroll
    for (int r = 0; r < 4; ++r) acc[r] = Wm[(i0 + ty + 8 * r) * 512 + d0 + tx];
    for (int c0 = 0; c0 < 512; c0 += 32) {
#pragma unroll
        for (int r = 0; r < 4; ++r) {
            As[ty + 8 * r][tx] = Wm[(i0 + ty + 8 * r) * 512 + c0 + tx];
            Bs[ty + 8 * r][tx] = AT[(c0 + ty + 8 * r) * 512 + d0 + tx];
        }
        __syncthreads();
#pragma unroll
        for (int c = 0; c < 32; ++c)
#pragma unroll
            for (int r = 0; r < 4; ++r) acc[r] += As[ty + 8 * r][c] * Bs[c][tx];
        __syncthreads();
    }
#pragma unroll
    for (int r = 0; r < 4; ++r) g_WmA[(i0 + ty + 8 * r) * 512 + d0 + tx] = acc[r];
}

// Build W_full in MFMA-B-fragment-swizzled order, split f16 hi/lo (lo x2048).
// swizzled index s = ((p*48 + kt)*64 + lane)*8 + j
//   n = p*16 + (lane&15),  k = kt*32 + ((lane>>4)&3)*8 + j
__global__ void prep_wfull(const float* __restrict__ Wh, const float* __restrict__ AT,
                           const float* __restrict__ BT, const float* __restrict__ eh,
                           const float* __restrict__ em, const float* __restrict__ ex,
                           const float* __restrict__ Wx) {
    int s = blockIdx.x * 256 + threadIdx.x;     // [0, 96*48*64*8) exactly
    int j8 = s & 7;
    int t = s >> 3;
    int lane = t & 63;
    t >>= 6;
    int kt = t % 48;
    int p = t / 48;
    int n = p * 16 + (lane & 15);
    int k = kt * 32 + ((lane >> 4) & 3) * 8 + j8;

    float w;
    if (n < 1024) {
        if (k < 1024) w = Wh[n * 1024 + k] + g_WmB[n] * eh[k];
        else          w = g_WmA[n * 512 + (k - 1024)] + g_WmB[n] * em[k - 1024];
    } else {
        int c = n - 1024;
        if (k < 1024) w = BT[c] * eh[k];
        else {
            int d = k - 1024;
            w = ((c == d) ? 1.f : 0.f) + AT[c * 512 + d] + BT[c] * em[d];
        }
    }
    _Float16 hi = (_Float16)w;
    g_Whi[s] = hi;
    g_Wlo[s] = (_Float16)((w - (float)hi) * LO_SCALE);

    if (s < NSTATE) {
        float b = (s < 1024) ? (Wx[s] + ex[0] * g_WmB[s]) : (BT[s - 1024] * ex[0]);
        g_wb[s] = b;
    }
    if (s < 2 * BATCH * NSTATE) { g_Shi[s] = (_Float16)0.f; g_Slo[s] = (_Float16)0.f; }
    if (s < 4096) g_bar[s] = 0u;
}

__launch_bounds__(256, 1)
__global__ void lmu_persist(const float* __restrict__ inputs,
                            const float* __restrict__ Wd, const float* __restrict__ bd,
                            float* __restrict__ out) {
    __shared__ half8 lwh[KTILES * 64];          // W_hi slice: 48 KB
    __shared__ half8 lwl[KTILES * 64];          // W_lo slice: 48 KB (96 KB total)

    const int tid = threadIdx.x;
    const int bid = blockIdx.x;
    const int g = (bid >> 2) & 1;               // batch group
    const int p = (bid >> 3) * 4 + (bid & 3);   // column tile [0,96)

    // stage W_hi + W_lo (global, swizzled-linear) -> LDS
    {
        const half8* srcH = (const half8*)(g_Whi + (size_t)p * WPW);
        const half8* srcL = (const half8*)(g_Wlo + (size_t)p * WPW);
        for (int i = tid; i < WPW / 8; i += 256) { lwh[i] = srcH[i]; lwl[i] = srcL[i]; }
    }

    const int lane = tid & 63, wv = tid >> 6;
    const int quad = lane >> 4, l16 = lane & 15;
    const int b0 = g * 64 + wv * 16;            // this wave's 16-row block
    const int n = p * 16 + l16;                 // this lane's output column
    const float wbv = g_wb[n];
    const bool do_tanh = (p < 64);

    // hierarchical barrier pointers (each counter in its own 256B sector)
    unsigned* const barb = g_bar + g * 2048;
    unsigned* const leaf = barb + (p >> 3) * 64;
    unsigned* const go   = barb + (12 + (p >> 3)) * 64;
    unsigned* const root = barb + 24 * 64;
    const bool leader = (p & 7) == 0;

    __syncthreads();

    const int rowA = b0 + l16;                  // A-fragment row for this lane
    const int kbase = quad * 8;

    int buf = 0;
    for (int t = 0; t < TSTEPS; ++t) {
        // normal cached loads: one LLC->L2 fill serves 12 WGs on this XCD
        const _Float16* shr = g_Shi + buf * BATCH * NSTATE + rowA * NSTATE + kbase;
        const _Float16* slr = g_Slo + buf * BATCH * NSTATE + rowA * NSTATE + kbase;

        const float* xt = inputs + t * BATCH;
        float xv[4];
#pragma unroll
        for (int r = 0; r < 4; ++r) xv[r] = xt[b0 + quad * 4 + r];

        floatx4 aA[2], aB[2], aC[2];
#pragma unroll
        for (int q = 0; q < 2; ++q) { aA[q] = (floatx4)0.f; aB[q] = (floatx4)0.f; aC[q] = (floatx4)0.f; }

#pragma unroll
        for (int kt = 0; kt < KTILES; ++kt) {
            half8 ah = *(const half8*)(shr + kt * 32);
            half8 al = *(const half8*)(slr + kt * 32);
            half8 bh = lwh[kt * 64 + lane];
            half8 bl = lwl[kt * 64 + lane];
            aA[kt & 1] = __builtin_amdgcn_mfma_f32_16x16x32_f16(ah, bh, aA[kt & 1], 0, 0, 0);
            aB[kt & 1] = __builtin_amdgcn_mfma_f32_16x16x32_f16(al, bh, aB[kt & 1], 0, 0, 0);
            aC[kt & 1] = __builtin_amdgcn_mfma_f32_16x16x32_f16(ah, bl, aC[kt & 1], 0, 0, 0);
        }

        // epilogue: bias + activation, split hi/lo; volatile = write-through,
        // so the LLC is always fresh and no release/wbl2 is ever needed.
        const int nbuf = buf ^ 1;
        volatile _Float16* dh = g_Shi + nbuf * BATCH * NSTATE;
        volatile _Float16* dl = g_Slo + nbuf * BATCH * NSTATE;
#pragma unroll
        for (int r = 0; r < 4; ++r) {
            int b = b0 + quad * 4 + r;
            float v = (aA[0][r] + aA[1][r])
                    + ((aB[0][r] + aB[1][r]) + (aC[0][r] + aC[1][r])) * LO_INV;
            v += xv[r] * wbv;
            if (do_tanh) v = tanhf(v);
            _Float16 hi = (_Float16)v;
            dh[b * NSTATE + n] = hi;
            dl[b * NSTATE + n] = (_Float16)((v - (float)hi) * LO_SCALE);
        }

        // ---- hierarchical group barrier: relaxed atomics, sleep backoff ----
        __builtin_amdgcn_fence(__ATOMIC_RELEASE, "workgroup");  // compiler order
        __syncthreads();                        // drains vmcnt: stores at LLC
        if (tid == 0) {
            const unsigned t1 = (unsigned)(t + 1);
            if (leader) {
                unsigned old = __hip_atomic_fetch_add(leaf, 1u, __ATOMIC_RELAXED,
                                                      __HIP_MEMORY_SCOPE_AGENT);
                if (old != 8u * t1 - 1u) {      // wait for my 7 members
                    int spin = 0;
                    while (__hip_atomic_load(leaf, __ATOMIC_RELAXED,
                                             __HIP_MEMORY_SCOPE_AGENT) < 8u * t1) {
                        __builtin_amdgcn_s_sleep(1);
                        if (++spin > (1 << 17)) break;
                    }
                }
                old = __hip_atomic_fetch_add(root, 1u, __ATOMIC_RELAXED,
                                             __HIP_MEMORY_SCOPE_AGENT);
                if (old != 12u * t1 - 1u) {     // wait for other 11 leaders
                    int spin = 0;
                    while (__hip_atomic_load(root, __ATOMIC_RELAXED,
                                             __HIP_MEMORY_SCOPE_AGENT) < 12u * t1) {
                        __builtin_amdgcn_s_sleep(1);
                        if (++spin > (1 << 17)) break;
                    }
                }
                __hip_atomic_fetch_add(go, 1u, __ATOMIC_RELAXED,
                                       __HIP_MEMORY_SCOPE_AGENT);
            } else {
                __hip_atomic_fetch_add(leaf, 1u, __ATOMIC_RELAXED,
                                       __HIP_MEMORY_SCOPE_AGENT);
                int spin = 0;
                while (__hip_atomic_load(go, __ATOMIC_RELAXED,
                                         __HIP_MEMORY_SCOPE_AGENT) < t1) {
                    __builtin_amdgcn_s_sleep(4);
                    if (++spin > (1 << 17)) break;
                }
            }
        }
        __syncthreads();
        // one inv per wave per step (L2 is clean: write-through stores) —
        // makes remote XCDs' state stores visible to next step's cached loads
        __builtin_amdgcn_fence(__ATOMIC_ACQUIRE, "agent");
        buf = nbuf;
    }

    // final epilogue: logits + softmax. WGs p<64 each own one batch row. buf==0.
    if (p < 64) {
        int b = g * 64 + p;
        const _Float16* sh = g_Shi + b * NSTATE;
        const _Float16* sl = g_Slo + b * NSTATE;
        __syncthreads();                         // smem reuse
        float* red = (float*)lwh;                // [16 chunks][16 cols] + [10 logits]
        int c = tid & 15, chunk = tid >> 4;
        float part = 0.f;
        if (c < 10) {
            for (int i = chunk * 64; i < chunk * 64 + 64; ++i)
                part += ((float)sh[i] + (float)sl[i] * LO_INV) * Wd[c * 1024 + i];
        }
        red[chunk * 16 + c] = part;
        __syncthreads();
        if (tid < 10) {
            float lg = bd[tid];
            for (int q = 0; q < 16; ++q) lg += red[q * 16 + tid];
            red[256 + tid] = lg;
        }
        __syncthreads();
        if (tid < 10) {
            float mx = red[256];
            for (int q = 1; q < 10; ++q) mx = fmaxf(mx, red[256 + q]);
            float sm = 0.f;
            for (int q = 0; q < 10; ++q) sm += expf(red[256 + q] - mx);
            out[b * 10 + tid] = expf(red[256 + tid] - mx) / sm;
        }
    }
}

extern "C" void kernel_launch(void* const* d_in, const int* in_sizes, int n_in,
                              void* d_out, int out_size, void* d_ws, size_t ws_size,
                              hipStream_t stream) {
    const float* inputs = (const float*)d_in[0];
    const float* e_x    = (const float*)d_in[1];
    const float* e_h    = (const float*)d_in[2];
    const float* e_m    = (const float*)d_in[3];
    const float* W_x    = (const float*)d_in[4];
    const float* W_h    = (const float*)d_in[5];
    const float* W_m    = (const float*)d_in[6];
    const float* AT     = (const float*)d_in[7];
    const float* BT     = (const float*)d_in[8];
    const float* W_d    = (const float*)d_in[9];
    const float* b_d    = (const float*)d_in[10];
    (void)d_ws; (void)ws_size; (void)in_sizes; (void)n_in;

    prep_wmb<<<256, 256, 0, stream>>>(W_m, BT);
    prep_wma<<<dim3(16, 32), 256, 0, stream>>>(W_m, AT);
    prep_wfull<<<9216, 256, 0, stream>>>(W_h, AT, BT, e_h, e_m, e_x, W_x);

    lmu_persist<<<192, 256, 0, stream>>>(inputs, W_d, b_d, (float*)d_out);
}

// Round 7
// 13184.030 us; speedup vs baseline: 1.6539x; 1.2802x over previous
//
#include <hip/hip_runtime.h>
#include <hip/hip_fp16.h>
#include <cmath>

// ---------------------------------------------------------------------------
// LMU fused recurrence.  One 128x1536 @ 1536x1536 GEMM per step (tanh on
// first 1024 cols, linear on last 512), x-dependent rank-1 bias.
// Persistent kernel, 192 WGs x 256 thr (1 WG/CU), 2 batch groups x 96 WGs.
// Precision (verified r3-r6, absmax 4.9e-4): f16 hi/lo weights AND state
// (lo planes x2048), fp32 MFMA accumulate, 3 products.
// r7 theory: r4/r6's 21us/step floor = 24 per-WG agent-acquire fences
// (buffer_inv sc1 = full L2 invalidate) per XCD per step, serializing at the
// TCC and repeatedly killing neighbors' L2 state fills.  Fix: ONE inv per
// XCD per group-step, done by an elected per-(group,XCD) leader (real XCD id
// via s_getreg HW_REG_XCC_ID; runtime registration so ANY dispatch mapping
// is correct).  Members only do a cheap CU-local L1 buffer_inv and read the
// leader-refreshed shared L2.  Producers keep volatile (write-through) state
// stores -> LLC always fresh -> no release walk needed anywhere.
// ---------------------------------------------------------------------------

typedef _Float16 half8 __attribute__((ext_vector_type(8)));
typedef float floatx4 __attribute__((ext_vector_type(4)));

#define NSTATE   1536
#define BATCH    128
#define TSTEPS   784
#define KTILES   48                 // 1536 / 32
#define GRP_WGS  96                 // WGs per batch group
#define WPW      24576              // weight elems per WG slice (16 cols * 1536)
#define LO_SCALE 2048.0f
#define LO_INV   (1.0f / 2048.0f)

// g_bar layout (unsigned words), all counters in own 256B sectors:
//   [ (g*8+x)*64 ]           leaf arrival counters      (0..1023)
//   [ 1024 + (g*8+x)*64 ]    go words                   (1024..2047)
//   [ 2048 + g*64 ]          root counters              (2048..2111)
//   [ 2176 + g*8+x ]         member counts (registration)
//   [ 2200 + g ]             nleaf per group
//   [ 2204 + g ]             one-time init barrier
__device__ unsigned g_bar[4096];

__device__ __align__(16) _Float16 g_Whi[96 * WPW];
__device__ __align__(16) _Float16 g_Wlo[96 * WPW];
__device__ float    g_wb[NSTATE];
__device__ float    g_WmA[1024 * 512];
__device__ float    g_WmB[1024];
__device__ __align__(16) _Float16 g_Shi[2 * BATCH * NSTATE];
__device__ __align__(16) _Float16 g_Slo[2 * BATCH * NSTATE];

// W_mB[i] = sum_c W_m[i,c] * BT[c]   (one wave per row, shuffle reduce)
__global__ void prep_wmb(const float* __restrict__ Wm, const float* __restrict__ BT) {
    int row  = blockIdx.x * 4 + (threadIdx.x >> 6);
    int lane = threadIdx.x & 63;
    float s = 0.f;
    for (int c = lane; c < 512; c += 64) s += Wm[row * 512 + c] * BT[c];
    for (int o = 32; o; o >>= 1) s += __shfl_down(s, o);
    if (lane == 0) g_WmB[row] = s;
}

// W_mA = W_m @ (I + AT) : tiled 32x32, fp32
__global__ void prep_wma(const float* __restrict__ Wm, const float* __restrict__ AT) {
    __shared__ float As[32][33], Bs[32][33];
    int d0 = blockIdx.x * 32, i0 = blockIdx.y * 32;
    int tx = threadIdx.x & 31, ty = threadIdx.x >> 5;   // ty in 0..7
    float acc[4];
#pragma unroll
    for (int r = 0; r < 4; ++r) acc[r] = Wm[(i0 + ty + 8 * r) * 512 + d0 + tx];
    for (int c0 = 0; c0 < 512; c0 += 32) {
#pragma unroll
        for (int r = 0; r < 4; ++r) {
            As[ty + 8 * r][tx] = Wm[(i0 + ty + 8 * r) * 512 + c0 + tx];
            Bs[ty + 8 * r][tx] = AT[(c0 + ty + 8 * r) * 512 + d0 + tx];
        }
        __syncthreads();
#pragma unroll
        for (int c = 0; c < 32; ++c)
#pragma unroll
            for (int r = 0; r < 4; ++r) acc[r] += As[ty + 8 * r][c] * Bs[c][tx];
        __syncthreads();
    }
#pragma unroll
    for (int r = 0; r < 4; ++r) g_WmA[(i0 + ty + 8 * r) * 512 + d0 + tx] = acc[r];
}

// Build W_full in MFMA-B-fragment-swizzled order, split f16 hi/lo (lo x2048).
// swizzled index s = ((p*48 + kt)*64 + lane)*8 + j
//   n = p*16 + (lane&15),  k = kt*32 + ((lane>>4)&3)*8 + j
__global__ void prep_wfull(const float* __restrict__ Wh, const float* __restrict__ AT,
                           const float* __restrict__ BT, const float* __restrict__ eh,
                           const float* __restrict__ em, const float* __restrict__ ex,
                           const float* __restrict__ Wx) {
    int s = blockIdx.x * 256 + threadIdx.x;     // [0, 96*48*64*8) exactly
    int j8 = s & 7;
    int t = s >> 3;
    int lane = t & 63;
    t >>= 6;
    int kt = t % 48;
    int p = t / 48;
    int n = p * 16 + (lane & 15);
    int k = kt * 32 + ((lane >> 4) & 3) * 8 + j8;

    float w;
    if (n < 1024) {
        if (k < 1024) w = Wh[n * 1024 + k] + g_WmB[n] * eh[k];
        else          w = g_WmA[n * 512 + (k - 1024)] + g_WmB[n] * em[k - 1024];
    } else {
        int c = n - 1024;
        if (k < 1024) w = BT[c] * eh[k];
        else {
            int d = k - 1024;
            w = ((c == d) ? 1.f : 0.f) + AT[c * 512 + d] + BT[c] * em[d];
        }
    }
    _Float16 hi = (_Float16)w;
    g_Whi[s] = hi;
    g_Wlo[s] = (_Float16)((w - (float)hi) * LO_SCALE);

    if (s < NSTATE) {
        float b = (s < 1024) ? (Wx[s] + ex[0] * g_WmB[s]) : (BT[s - 1024] * ex[0]);
        g_wb[s] = b;
    }
    if (s < 2 * BATCH * NSTATE) { g_Shi[s] = (_Float16)0.f; g_Slo[s] = (_Float16)0.f; }
    if (s < 4096) g_bar[s] = 0u;
}

__launch_bounds__(256, 1)
__global__ void lmu_persist(const float* __restrict__ inputs,
                            const float* __restrict__ Wd, const float* __restrict__ bd,
                            float* __restrict__ out) {
    __shared__ half8 lwh[KTILES * 64];          // W_hi slice: 48 KB
    __shared__ half8 lwl[KTILES * 64];          // W_lo slice: 48 KB (96 KB total)

    const int tid = threadIdx.x;
    const int bid = blockIdx.x;
    const int g = (bid >> 2) & 1;               // batch group
    const int p = (bid >> 3) * 4 + (bid & 3);   // column tile [0,96)

    // stage W_hi + W_lo (global, swizzled-linear) -> LDS
    {
        const half8* srcH = (const half8*)(g_Whi + (size_t)p * WPW);
        const half8* srcL = (const half8*)(g_Wlo + (size_t)p * WPW);
        for (int i = tid; i < WPW / 8; i += 256) { lwh[i] = srcH[i]; lwl[i] = srcL[i]; }
    }

    const int lane = tid & 63, wv = tid >> 6;
    const int quad = lane >> 4, l16 = lane & 15;
    const int b0 = g * 64 + wv * 16;            // this wave's 16-row block
    const int n = p * 16 + l16;                 // this lane's output column
    const float wbv = g_wb[n];
    const bool do_tanh = (p < 64);

    // ---- real XCD id (wave-uniform; m09-verified on gfx950) ----
    unsigned xcd;
    asm volatile("s_getreg_b32 %0, hwreg(HW_REG_XCC_ID)" : "=s"(xcd));
    xcd &= 7u;

    unsigned* const leaf = g_bar + (g * 8 + xcd) * 64;
    unsigned* const go   = g_bar + 1024 + (g * 8 + xcd) * 64;
    unsigned* const root = g_bar + 2048 + g * 64;
    unsigned* const memb = g_bar + 2176 + g * 8 + xcd;
    unsigned* const nlfp = g_bar + 2200 + g;
    unsigned* const init = g_bar + 2204 + g;

    // ---- one-time registration: member count / leader / leaf count ----
    unsigned rank = 0, leafN = 0, nleaf = 0;
    if (tid == 0) {
        rank = __hip_atomic_fetch_add(memb, 1u, __ATOMIC_RELAXED,
                                      __HIP_MEMORY_SCOPE_AGENT);
        if (rank == 0)
            __hip_atomic_fetch_add(nlfp, 1u, __ATOMIC_RELAXED,
                                   __HIP_MEMORY_SCOPE_AGENT);
        __builtin_amdgcn_s_waitcnt(0);          // regs globally performed
        __hip_atomic_fetch_add(init, 1u, __ATOMIC_RELAXED,
                               __HIP_MEMORY_SCOPE_AGENT);
        int spin = 0;
        while (__hip_atomic_load(init, __ATOMIC_RELAXED,
                                 __HIP_MEMORY_SCOPE_AGENT) < (unsigned)GRP_WGS) {
            __builtin_amdgcn_s_sleep(2);
            if (++spin > (1 << 20)) break;      // deadman
        }
        leafN = __hip_atomic_load(memb, __ATOMIC_RELAXED, __HIP_MEMORY_SCOPE_AGENT);
        nleaf = __hip_atomic_load(nlfp, __ATOMIC_RELAXED, __HIP_MEMORY_SCOPE_AGENT);
    }
    __syncthreads();

    const int rowA = b0 + l16;                  // A-fragment row for this lane
    const int kbase = quad * 8;

    int buf = 0;
    for (int t = 0; t < TSTEPS; ++t) {
        // plain cached loads: one LLC->L2 fill per XCD serves all local WGs
        const _Float16* shr = g_Shi + buf * BATCH * NSTATE + rowA * NSTATE + kbase;
        const _Float16* slr = g_Slo + buf * BATCH * NSTATE + rowA * NSTATE + kbase;

        const float* xt = inputs + t * BATCH;
        float xv[4];
#pragma unroll
        for (int r = 0; r < 4; ++r) xv[r] = xt[b0 + quad * 4 + r];

        floatx4 aA[2], aB[2], aC[2];
#pragma unroll
        for (int q = 0; q < 2; ++q) { aA[q] = (floatx4)0.f; aB[q] = (floatx4)0.f; aC[q] = (floatx4)0.f; }

#pragma unroll
        for (int kt = 0; kt < KTILES; ++kt) {
            half8 ah = *(const half8*)(shr + kt * 32);
            half8 al = *(const half8*)(slr + kt * 32);
            half8 bh = lwh[kt * 64 + lane];
            half8 bl = lwl[kt * 64 + lane];
            aA[kt & 1] = __builtin_amdgcn_mfma_f32_16x16x32_f16(ah, bh, aA[kt & 1], 0, 0, 0);
            aB[kt & 1] = __builtin_amdgcn_mfma_f32_16x16x32_f16(al, bh, aB[kt & 1], 0, 0, 0);
            aC[kt & 1] = __builtin_amdgcn_mfma_f32_16x16x32_f16(ah, bl, aC[kt & 1], 0, 0, 0);
        }

        // epilogue: bias + activation, split hi/lo; volatile = write-through,
        // LLC always fresh -> no release/wbl2 walk ever needed.
        const int nbuf = buf ^ 1;
        volatile _Float16* dh = g_Shi + nbuf * BATCH * NSTATE;
        volatile _Float16* dl = g_Slo + nbuf * BATCH * NSTATE;
#pragma unroll
        for (int r = 0; r < 4; ++r) {
            int b = b0 + quad * 4 + r;
            float v = (aA[0][r] + aA[1][r])
                    + ((aB[0][r] + aB[1][r]) + (aC[0][r] + aC[1][r])) * LO_INV;
            v += xv[r] * wbv;
            if (do_tanh) v = tanhf(v);
            _Float16 hi = (_Float16)v;
            dh[b * NSTATE + n] = hi;
            dl[b * NSTATE + n] = (_Float16)((v - (float)hi) * LO_SCALE);
        }

        // ---- barrier + leader-consolidated L2 invalidate ----
        __builtin_amdgcn_fence(__ATOMIC_RELEASE, "workgroup");  // compiler order
        __syncthreads();                        // drains vmcnt: stores at LLC
        if (tid == 0) {
            const unsigned t1 = (unsigned)(t + 1);
            __hip_atomic_fetch_add(leaf, 1u, __ATOMIC_RELAXED,
                                   __HIP_MEMORY_SCOPE_AGENT);
            if (rank == 0) {
                // leaf leader: wait local members, then root, then ONE L2 inv
                int spin = 0;
                while (__hip_atomic_load(leaf, __ATOMIC_RELAXED,
                                         __HIP_MEMORY_SCOPE_AGENT) < leafN * t1) {
                    __builtin_amdgcn_s_sleep(1);
                    if (++spin > (1 << 17)) break;
                }
                __hip_atomic_fetch_add(root, 1u, __ATOMIC_RELAXED,
                                       __HIP_MEMORY_SCOPE_AGENT);
                spin = 0;
                while (__hip_atomic_load(root, __ATOMIC_RELAXED,
                                         __HIP_MEMORY_SCOPE_AGENT) < nleaf * t1) {
                    __builtin_amdgcn_s_sleep(1);
                    if (++spin > (1 << 17)) break;
                }
                // one L2(+L1) invalidate for this XCD-group, wait completion
                __builtin_amdgcn_fence(__ATOMIC_ACQUIRE, "agent");
                __builtin_amdgcn_s_waitcnt(0);
                __hip_atomic_fetch_add(go, 1u, __ATOMIC_RELAXED,
                                       __HIP_MEMORY_SCOPE_AGENT);
            } else {
                int spin = 0;
                while (__hip_atomic_load(go, __ATOMIC_RELAXED,
                                         __HIP_MEMORY_SCOPE_AGENT) < t1) {
                    __builtin_amdgcn_s_sleep(2);
                    if (++spin > (1 << 17)) break;
                }
                // members: CU-local L1 invalidate only (L2 refreshed by leader)
                asm volatile("buffer_inv" ::: "memory");
            }
        }
        __syncthreads();
        __builtin_amdgcn_fence(__ATOMIC_ACQUIRE, "workgroup"); // compiler order
        buf = nbuf;
    }

    // final epilogue: logits + softmax. WGs p<64 each own one batch row. buf==0.
    if (p < 64) {
        int b = g * 64 + p;
        const _Float16* sh = g_Shi + b * NSTATE;
        const _Float16* sl = g_Slo + b * NSTATE;
        __syncthreads();                         // smem reuse
        float* red = (float*)lwh;                // [16 chunks][16 cols] + [10 logits]
        int c = tid & 15, chunk = tid >> 4;
        float part = 0.f;
        if (c < 10) {
            for (int i = chunk * 64; i < chunk * 64 + 64; ++i)
                part += ((float)sh[i] + (float)sl[i] * LO_INV) * Wd[c * 1024 + i];
        }
        red[chunk * 16 + c] = part;
        __syncthreads();
        if (tid < 10) {
            float lg = bd[tid];
            for (int q = 0; q < 16; ++q) lg += red[q * 16 + tid];
            red[256 + tid] = lg;
        }
        __syncthreads();
        if (tid < 10) {
            float mx = red[256];
            for (int q = 1; q < 10; ++q) mx = fmaxf(mx, red[256 + q]);
            float sm = 0.f;
            for (int q = 0; q < 10; ++q) sm += expf(red[256 + q] - mx);
            out[b * 10 + tid] = expf(red[256 + tid] - mx) / sm;
        }
    }
}

extern "C" void kernel_launch(void* const* d_in, const int* in_sizes, int n_in,
                              void* d_out, int out_size, void* d_ws, size_t ws_size,
                              hipStream_t stream) {
    const float* inputs = (const float*)d_in[0];
    const float* e_x    = (const float*)d_in[1];
    const float* e_h    = (const float*)d_in[2];
    const float* e_m    = (const float*)d_in[3];
    const float* W_x    = (const float*)d_in[4];
    const float* W_h    = (const float*)d_in[5];
    const float* W_m    = (const float*)d_in[6];
    const float* AT     = (const float*)d_in[7];
    const float* BT     = (const float*)d_in[8];
    const float* W_d    = (const float*)d_in[9];
    const float* b_d    = (const float*)d_in[10];
    (void)d_ws; (void)ws_size; (void)in_sizes; (void)n_in;

    prep_wmb<<<256, 256, 0, stream>>>(W_m, BT);
    prep_wma<<<dim3(16, 32), 256, 0, stream>>>(W_m, AT);
    prep_wfull<<<9216, 256, 0, stream>>>(W_h, AT, BT, e_h, e_m, e_x, W_x);

    lmu_persist<<<192, 256, 0, stream>>>(inputs, W_d, b_d, (float*)d_out);
}